// Round 4
// baseline (241.284 us; speedup 1.0000x reference)
//
#include <hip/hip_runtime.h>
#include <stdint.h>
#include <stddef.h>

#define B_      8
#define T_      16
#define NX_     256
#define NZ_     64
#define D_      1024
#define HEADS_  8
#define DHEAD_  64
#define INNER_  512
#define NKEY_   320          // NX_ + NZ_
#define NBT_    128          // B_*T_

typedef __attribute__((ext_vector_type(8))) short     short8;
typedef __attribute__((ext_vector_type(4))) float     f32x4;
typedef __attribute__((ext_vector_type(8))) unsigned short u16x8;

__device__ __forceinline__ unsigned short f2bf(float f) {
    union { float f; unsigned int u; } v; v.f = f;
    unsigned int u = v.u;
    return (unsigned short)((u + 0x7fffu + ((u >> 16) & 1u)) >> 16);
}

__device__ __forceinline__ void async16(unsigned short* lds, const unsigned short* g) {
    __builtin_amdgcn_global_load_lds(
        (const __attribute__((address_space(1))) void*)g,
        (__attribute__((address_space(3))) void*)lds, 16, 0, 0);
}

// ---------------------------------------------------------------------------
// mask normalization: handles both bool-byte and int32 storage of mask[128]
// ---------------------------------------------------------------------------
__global__ void mask_kernel(const unsigned char* __restrict__ mraw,
                            int* __restrict__ maskN) {
    int lane = threadIdx.x;                 // 64 threads
    unsigned char b0 = mraw[lane];
    unsigned char b1 = mraw[lane + 64];
    bool nz = (((lane) & 3) != 0 && b0 != 0) || (((lane + 64) & 3) != 0 && b1 != 0);
    unsigned long long ball = __ballot(nz ? 1 : 0);
    bool isBool = (ball != 0ull);
    int v0, v1;
    if (isBool) { v0 = b0; v1 = b1; }
    else        { v0 = mraw[4 * lane]; v1 = mraw[4 * (lane + 64)]; }
    maskN[lane]      = v0 ? 1 : 0;
    maskN[lane + 64] = v1 ? 1 : 0;
}

// ---------------------------------------------------------------------------
// weight prep: f32 -> bf16, transposed to [N][K]
// ---------------------------------------------------------------------------
__global__ __launch_bounds__(256) void wprep_kernel(
        const float* __restrict__ Wq, const float* __restrict__ Wkv,
        const float* __restrict__ Wo,
        unsigned short* __restrict__ WqT, unsigned short* __restrict__ WkvT,
        unsigned short* __restrict__ WoT) {
    size_t id = (size_t)blockIdx.x * 256 + threadIdx.x;
    if (id < 524288) {                       // WqT[512][1024] <- Wq[1024][512]
        int n = (int)(id >> 10), k = (int)(id & 1023);
        WqT[id] = f2bf(Wq[(size_t)k * 512 + n]);
    } else if (id < 524288 + 1048576) {      // WkvT[1024][1024] <- Wkv[1024][1024]
        size_t j = id - 524288;
        int n = (int)(j >> 10), k = (int)(j & 1023);
        WkvT[j] = f2bf(Wkv[(size_t)k * 1024 + n]);
    } else {                                 // WoT[1024][512] <- Wo[512][1024]
        size_t j = id - 1572864;
        int n = (int)(j >> 9), k = (int)(j & 511);
        WoT[j] = f2bf(Wo[(size_t)k * 1024 + n]);
    }
}

// ---------------------------------------------------------------------------
// LayerNorm rows of x (32768) and latents (8192) -> bf16 packed kvin
// kvin[bt][0..255][1024] = xn rows, kvin[bt][256..319][1024] = zn rows
// ---------------------------------------------------------------------------
__global__ __launch_bounds__(256) void ln_kernel(
        const float* __restrict__ x, const float* __restrict__ lat,
        const float* __restrict__ gm, const float* __restrict__ bm,
        const float* __restrict__ gl, const float* __restrict__ bl,
        const int* __restrict__ maskN,
        unsigned short* __restrict__ kvin) {
    int row = blockIdx.x;
    const float* src; unsigned short* dst; const float* g; const float* b;
    int bt;
    if (row < NBT_ * NX_) {
        bt = row >> 8;
        src = x + (size_t)row * D_;
        dst = kvin + ((size_t)bt * NKEY_ + (row & 255)) * D_;
        g = gm; b = bm;
    } else {
        int r = row - NBT_ * NX_;
        bt = r >> 6;
        src = lat + (size_t)r * D_;
        dst = kvin + ((size_t)bt * NKEY_ + 256 + (r & 63)) * D_;
        g = gl; b = bl;
    }
    if (!maskN[bt]) return;                  // masked (b,t): values never read
    int t = threadIdx.x;
    float4 v = reinterpret_cast<const float4*>(src)[t];
    float s  = v.x + v.y + v.z + v.w;
    float sq = v.x * v.x + v.y * v.y + v.z * v.z + v.w * v.w;
    #pragma unroll
    for (int off = 32; off > 0; off >>= 1) {
        s  += __shfl_down(s, off);
        sq += __shfl_down(sq, off);
    }
    __shared__ float red[8];
    int wid = t >> 6;
    if ((t & 63) == 0) { red[wid] = s; red[4 + wid] = sq; }
    __syncthreads();
    float stot = red[0] + red[1] + red[2] + red[3];
    float qtot = red[4] + red[5] + red[6] + red[7];
    float mean = stot * (1.0f / 1024.0f);
    float var  = qtot * (1.0f / 1024.0f) - mean * mean;
    float rstd = rsqrtf(var + 1e-5f);
    float4 gv = reinterpret_cast<const float4*>(g)[t];
    float4 bv = reinterpret_cast<const float4*>(b)[t];
    ushort4 o;
    o.x = f2bf((v.x - mean) * rstd * gv.x + bv.x);
    o.y = f2bf((v.y - mean) * rstd * gv.y + bv.y);
    o.z = f2bf((v.z - mean) * rstd * gv.z + bv.z);
    o.w = f2bf((v.w - mean) * rstd * gv.w + bv.w);
    *reinterpret_cast<ushort4*>(dst + 4 * t) = o;
}

// ---------------------------------------------------------------------------
// 2-phase double-buffered GEMM (T3-minimum): 128x128 tile, BK=64, 4 waves,
// global_load_lds width-16 staging into buf^1 issued BEFORE computing buf,
// ONE __syncthreads per K-step (implicit vmcnt(0)+lgkmcnt(0) drain).
// MODE 0: q  [8192][512]  = kvin-z rows @ WqT,  *0.125, bf16
// MODE 1: kv [40960][1024]= kvin @ WkvT -> k [bt][320][512], vT [bt][512][320]
// MODE 2: out[8192][1024] = ao @ WoT, f32, zeros for masked rows
// ---------------------------------------------------------------------------
template<int MODE>
__global__ __launch_bounds__(256) void gemm128_kernel(
        const unsigned short* __restrict__ A,
        const unsigned short* __restrict__ BT,
        const int* __restrict__ maskN,
        unsigned short* __restrict__ o_q,
        unsigned short* __restrict__ o_k,
        unsigned short* __restrict__ o_v,
        float* __restrict__ o_f) {
    constexpr int K     = (MODE == 2) ? 512 : 1024;
    constexpr int NSTEP = K / 64;
    constexpr int NT    = (MODE == 0) ? 4 : 8;                 // N-tiles
    constexpr int CHUNK = (MODE == 1) ? 320 : (MODE == 0 ? 32 : 64);

    int swz = (blockIdx.x & 7) * CHUNK + (blockIdx.x >> 3);    // XCD-chunked
    int nt = swz % NT, mt = swz / NT;
    int m0 = mt * 128, n0 = nt * 128;
    int t = threadIdx.x;
    int lane = t & 63, wid = t >> 6;
    int lr = lane & 15, lg = lane >> 4;
    int wm = wid >> 1, wn = wid & 1;

    // mask skip: which bt's does this row-tile touch?
    int bt0, bt1;
    if (MODE == 1) { bt0 = m0 / NKEY_; bt1 = (m0 + 127) / NKEY_; }
    else           { bt0 = m0 >> 6;    bt1 = bt0 + 1; }
    bool any = false;
    for (int b = bt0; b <= bt1; b++) any |= (maskN[b] != 0);
    if (!any) {
        if (MODE == 2) {                       // masked out rows must be zero
            int r = t >> 1, cb = (t & 1) * 64;
            float4 z = make_float4(0.f, 0.f, 0.f, 0.f);
            float4* p = reinterpret_cast<float4*>(o_f + (size_t)(m0 + r) * 1024 + n0 + cb);
            #pragma unroll
            for (int j = 0; j < 16; j++) p[j] = z;
        }
        return;
    }

    __shared__ __align__(16) unsigned short As[2][8192];   // 2 x 128x64
    __shared__ __align__(16) unsigned short Bs[2][8192];

    // per-lane global staging pointers (rows fixed, col advances)
    const unsigned short* aptr[4];
    const unsigned short* bptr[4];
    #pragma unroll
    for (int i = 0; i < 4; i++) {
        int row = m0 + wid * 32 + i * 8 + (lane >> 3);
        size_t srow;
        if (MODE == 0) { int bt = row >> 6; srow = (size_t)bt * NKEY_ + 256 + (row & 63); }
        else           srow = (size_t)row;
        aptr[i] = A  + srow * K + (lane & 7) * 8;
        int brow = n0 + wid * 32 + i * 8 + (lane >> 3);
        bptr[i] = BT + (size_t)brow * K + (lane & 7) * 8;
    }

    f32x4 acc[4][4];
    #pragma unroll
    for (int i = 0; i < 4; i++)
        #pragma unroll
        for (int j = 0; j < 4; j++) acc[i][j] = (f32x4){0.f, 0.f, 0.f, 0.f};

    // prologue: stage tile 0 into buf 0
    #pragma unroll
    for (int i = 0; i < 4; i++) {
        async16(&As[0][wid * 2048 + i * 512], aptr[i]);
        async16(&Bs[0][wid * 2048 + i * 512], bptr[i]);
        aptr[i] += 64; bptr[i] += 64;
    }
    __syncthreads();                            // drains vmcnt(0)

    for (int ks = 0; ks < NSTEP; ks++) {
        int cur = ks & 1;
        if (ks + 1 < NSTEP) {                   // issue next-tile loads FIRST
            #pragma unroll
            for (int i = 0; i < 4; i++) {
                async16(&As[cur ^ 1][wid * 2048 + i * 512], aptr[i]);
                async16(&Bs[cur ^ 1][wid * 2048 + i * 512], bptr[i]);
                aptr[i] += 64; bptr[i] += 64;
            }
        }
        #pragma unroll
        for (int kc = 0; kc < 2; kc++) {
            short8 af[4], bf[4];
            #pragma unroll
            for (int mi = 0; mi < 4; mi++)
                af[mi] = *reinterpret_cast<const short8*>(
                    &As[cur][(wm * 64 + mi * 16 + lr) * 64 + kc * 32 + lg * 8]);
            #pragma unroll
            for (int ni = 0; ni < 4; ni++)
                bf[ni] = *reinterpret_cast<const short8*>(
                    &Bs[cur][(wn * 64 + ni * 16 + lr) * 64 + kc * 32 + lg * 8]);
            #pragma unroll
            for (int mi = 0; mi < 4; mi++)
                #pragma unroll
                for (int ni = 0; ni < 4; ni++)
                    acc[mi][ni] = __builtin_amdgcn_mfma_f32_16x16x32_bf16(
                        af[mi], bf[ni], acc[mi][ni], 0, 0, 0);
        }
        __syncthreads();   // one barrier/step: drains next-stage vmcnt + lgkm
    }

    #pragma unroll
    for (int mi = 0; mi < 4; mi++)
        #pragma unroll
        for (int ni = 0; ni < 4; ni++) {
            int gr0 = m0 + wm * 64 + mi * 16 + lg * 4;     // +r, never crosses bt
            int c   = n0 + wn * 64 + ni * 16 + lr;
            if (MODE == 0) {
                #pragma unroll
                for (int r = 0; r < 4; r++)
                    o_q[(size_t)(gr0 + r) * 512 + c] = f2bf(acc[mi][ni][r] * 0.125f);
            } else if (MODE == 1) {
                int bt = gr0 / NKEY_;
                int krow = gr0 - bt * NKEY_;
                if (c < 512) {
                    #pragma unroll
                    for (int r = 0; r < 4; r++)
                        o_k[((size_t)bt * NKEY_ + krow + r) * 512 + c] = f2bf(acc[mi][ni][r]);
                } else {
                    ushort4 pv;
                    pv.x = f2bf(acc[mi][ni][0]); pv.y = f2bf(acc[mi][ni][1]);
                    pv.z = f2bf(acc[mi][ni][2]); pv.w = f2bf(acc[mi][ni][3]);
                    *reinterpret_cast<ushort4*>(
                        o_v + ((size_t)bt * 512 + (c - 512)) * NKEY_ + krow) = pv;
                }
            } else {
                int bt = gr0 >> 6;
                bool live = maskN[bt] != 0;
                #pragma unroll
                for (int r = 0; r < 4; r++)
                    o_f[(size_t)(gr0 + r) * 1024 + c] = live ? acc[mi][ni][r] : 0.0f;
            }
        }
}

// ---------------------------------------------------------------------------
// fused attention per (b,t,h): sim = q @ k^T (64x320), softmax, out = attn @ v
// ---------------------------------------------------------------------------
__global__ __launch_bounds__(256) void attn_kernel(
        const unsigned short* __restrict__ q,
        const unsigned short* __restrict__ kbuf,
        const unsigned short* __restrict__ vbuf,   // vT [bt][512][320]
        const int* __restrict__ maskN,
        unsigned short* __restrict__ ao) {
    const int nwg = gridDim.x;                     // 1024
    int bid = (blockIdx.x & 7) * (nwg >> 3) + (blockIdx.x >> 3);
    int bt = bid >> 3, h = bid & 7;
    if (!maskN[bt]) return;
    int t = threadIdx.x, w = t >> 6, lane = t & 63;
    int lr = lane & 15, lg = lane >> 4;
    __shared__ __align__(16) unsigned short attn_s[4][16][328];

    const unsigned short* qrow = q + ((size_t)bt * 64 + w * 16 + lr) * 512 + h * 64;
    short8 qa0 = *reinterpret_cast<const short8*>(qrow + lg * 8);
    short8 qa1 = *reinterpret_cast<const short8*>(qrow + 32 + lg * 8);

    f32x4 acc[20];
    #pragma unroll
    for (int i = 0; i < 20; i++) acc[i] = (f32x4){0.f, 0.f, 0.f, 0.f};

    const unsigned short* kb = kbuf + (size_t)bt * NKEY_ * 512 + h * 64;
    #pragma unroll
    for (int nt2 = 0; nt2 < 20; nt2++) {
        const unsigned short* krow = kb + (size_t)(nt2 * 16 + lr) * 512;
        short8 b0 = *reinterpret_cast<const short8*>(krow + lg * 8);
        short8 b1 = *reinterpret_cast<const short8*>(krow + 32 + lg * 8);
        acc[nt2] = __builtin_amdgcn_mfma_f32_16x16x32_bf16(qa0, b0, acc[nt2], 0, 0, 0);
        acc[nt2] = __builtin_amdgcn_mfma_f32_16x16x32_bf16(qa1, b1, acc[nt2], 0, 0, 0);
    }

    float mx[4], sm[4];
    #pragma unroll
    for (int r = 0; r < 4; r++) mx[r] = -1e30f;
    #pragma unroll
    for (int nt2 = 0; nt2 < 20; nt2++)
        #pragma unroll
        for (int r = 0; r < 4; r++) mx[r] = fmaxf(mx[r], acc[nt2][r]);
    #pragma unroll
    for (int r = 0; r < 4; r++) {
        #pragma unroll
        for (int off = 1; off < 16; off <<= 1)
            mx[r] = fmaxf(mx[r], __shfl_xor(mx[r], off));
        sm[r] = 0.f;
    }
    #pragma unroll
    for (int nt2 = 0; nt2 < 20; nt2++)
        #pragma unroll
        for (int r = 0; r < 4; r++) {
            float p = __expf(acc[nt2][r] - mx[r]);
            acc[nt2][r] = p;
            sm[r] += p;
        }
    #pragma unroll
    for (int r = 0; r < 4; r++) {
        #pragma unroll
        for (int off = 1; off < 16; off <<= 1)
            sm[r] += __shfl_xor(sm[r], off);
        sm[r] = 1.0f / sm[r];
    }
    #pragma unroll
    for (int nt2 = 0; nt2 < 20; nt2++)
        #pragma unroll
        for (int r = 0; r < 4; r++)
            attn_s[w][lg * 4 + r][nt2 * 16 + lr] = f2bf(acc[nt2][r] * sm[r]);
    __syncthreads();

    f32x4 o[4];
    #pragma unroll
    for (int i = 0; i < 4; i++) o[i] = (f32x4){0.f, 0.f, 0.f, 0.f};
    const unsigned short* vb = vbuf + (size_t)bt * 512 * NKEY_ + (size_t)h * 64 * NKEY_;
    #pragma unroll
    for (int kc = 0; kc < 10; kc++) {
        short8 pa = *reinterpret_cast<const short8*>(&attn_s[w][lr][kc * 32 + lg * 8]);
        #pragma unroll
        for (int ni = 0; ni < 4; ni++) {
            short8 vf = *reinterpret_cast<const short8*>(
                vb + (size_t)(ni * 16 + lr) * NKEY_ + kc * 32 + lg * 8);
            o[ni] = __builtin_amdgcn_mfma_f32_16x16x32_bf16(pa, vf, o[ni], 0, 0, 0);
        }
    }
    #pragma unroll
    for (int ni = 0; ni < 4; ni++)
        #pragma unroll
        for (int r = 0; r < 4; r++)
            ao[((size_t)bt * 64 + w * 16 + lg * 4 + r) * 512 + h * 64 + ni * 16 + lr] =
                f2bf(o[ni][r]);
}

// ---------------------------------------------------------------------------
extern "C" void kernel_launch(void* const* d_in, const int* in_sizes, int n_in,
                              void* d_out, int out_size, void* d_ws, size_t ws_size,
                              hipStream_t stream) {
    const float* x            = (const float*)d_in[0];
    const float* lat          = (const float*)d_in[1];
    const unsigned char* mraw = (const unsigned char*)d_in[2];
    const float* gm           = (const float*)d_in[3];
    const float* bm           = (const float*)d_in[4];
    const float* gl           = (const float*)d_in[5];
    const float* bl           = (const float*)d_in[6];
    const float* Wq           = (const float*)d_in[7];
    const float* Wkv          = (const float*)d_in[8];
    const float* Wo           = (const float*)d_in[9];
    float* out = (float*)d_out;

    char* ws = (char*)d_ws;
    size_t off = 0;
    int* maskN = (int*)(ws + off);             off += 1024;
    unsigned short* WqT  = (unsigned short*)(ws + off); off += 1048576;   // 512*1024*2
    unsigned short* WkvT = (unsigned short*)(ws + off); off += 2097152;   // 1024*1024*2
    unsigned short* WoT  = (unsigned short*)(ws + off); off += 1048576;   // 1024*512*2
    unsigned short* kvin = (unsigned short*)(ws + off); off += 83886080;  // 128*320*1024*2
    unsigned short* qb   = (unsigned short*)(ws + off); off += 8388608;   // 128*64*512*2
    unsigned short* kb   = (unsigned short*)(ws + off); off += 41943040;  // 128*320*512*2
    unsigned short* vb   = (unsigned short*)(ws + off); off += 41943040;  // 128*512*320*2
    unsigned short* ab   = (unsigned short*)(ws + off); off += 8388608;   // 128*64*512*2

    hipLaunchKernelGGL(mask_kernel,  dim3(1),     dim3(64),  0, stream, mraw, maskN);
    hipLaunchKernelGGL(wprep_kernel, dim3(8192),  dim3(256), 0, stream,
                       Wq, Wkv, Wo, WqT, WkvT, WoT);
    hipLaunchKernelGGL(ln_kernel,    dim3(40960), dim3(256), 0, stream,
                       x, lat, gm, bm, gl, bl, maskN, kvin);
    hipLaunchKernelGGL((gemm128_kernel<0>), dim3(256),  dim3(256), 0, stream,
                       kvin, WqT,  maskN, qb, kb, vb, out);
    hipLaunchKernelGGL((gemm128_kernel<1>), dim3(2560), dim3(256), 0, stream,
                       kvin, WkvT, maskN, qb, kb, vb, out);
    hipLaunchKernelGGL(attn_kernel,         dim3(1024), dim3(256), 0, stream,
                       qb, kb, vb, maskN, ab);
    hipLaunchKernelGGL((gemm128_kernel<2>), dim3(512),  dim3(256), 0, stream,
                       ab, WoT,  maskN, qb, kb, vb, out);
}

// Round 5
// 215.295 us; speedup vs baseline: 1.1207x; 1.1207x over previous
//
#include <hip/hip_runtime.h>
#include <stdint.h>
#include <stddef.h>

#define B_      8
#define T_      16
#define NX_     256
#define NZ_     64
#define D_      1024
#define HEADS_  8
#define DHEAD_  64
#define INNER_  512
#define NKEY_   320          // NX_ + NZ_
#define NBT_    128          // B_*T_

typedef __attribute__((ext_vector_type(8))) short     short8;
typedef __attribute__((ext_vector_type(4))) float     f32x4;
typedef __attribute__((ext_vector_type(8))) unsigned short u16x8;

__device__ __forceinline__ unsigned short f2bf(float f) {
    union { float f; unsigned int u; } v; v.f = f;
    unsigned int u = v.u;
    return (unsigned short)((u + 0x7fffu + ((u >> 16) & 1u)) >> 16);
}

__device__ __forceinline__ void async16(unsigned short* lds, const unsigned short* g) {
    __builtin_amdgcn_global_load_lds(
        (const __attribute__((address_space(1))) void*)g,
        (__attribute__((address_space(3))) void*)lds, 16, 0, 0);
}

// ---------------------------------------------------------------------------
// mask normalization: handles both bool-byte and int32 storage of mask[128]
// ---------------------------------------------------------------------------
__global__ void mask_kernel(const unsigned char* __restrict__ mraw,
                            int* __restrict__ maskN) {
    int lane = threadIdx.x;                 // 64 threads
    unsigned char b0 = mraw[lane];
    unsigned char b1 = mraw[lane + 64];
    bool nz = (((lane) & 3) != 0 && b0 != 0) || (((lane + 64) & 3) != 0 && b1 != 0);
    unsigned long long ball = __ballot(nz ? 1 : 0);
    bool isBool = (ball != 0ull);
    int v0, v1;
    if (isBool) { v0 = b0; v1 = b1; }
    else        { v0 = mraw[4 * lane]; v1 = mraw[4 * (lane + 64)]; }
    maskN[lane]      = v0 ? 1 : 0;
    maskN[lane + 64] = v1 ? 1 : 0;
}

// ---------------------------------------------------------------------------
// weight prep: f32 -> bf16, transposed to [N][K]
// ---------------------------------------------------------------------------
__global__ __launch_bounds__(256) void wprep_kernel(
        const float* __restrict__ Wq, const float* __restrict__ Wkv,
        const float* __restrict__ Wo,
        unsigned short* __restrict__ WqT, unsigned short* __restrict__ WkvT,
        unsigned short* __restrict__ WoT) {
    size_t id = (size_t)blockIdx.x * 256 + threadIdx.x;
    if (id < 524288) {                       // WqT[512][1024] <- Wq[1024][512]
        int n = (int)(id >> 10), k = (int)(id & 1023);
        WqT[id] = f2bf(Wq[(size_t)k * 512 + n]);
    } else if (id < 524288 + 1048576) {      // WkvT[1024][1024] <- Wkv[1024][1024]
        size_t j = id - 524288;
        int n = (int)(j >> 10), k = (int)(j & 1023);
        WkvT[j] = f2bf(Wkv[(size_t)k * 1024 + n]);
    } else {                                 // WoT[1024][512] <- Wo[512][1024]
        size_t j = id - 1572864;
        int n = (int)(j >> 9), k = (int)(j & 511);
        WoT[j] = f2bf(Wo[(size_t)k * 1024 + n]);
    }
}

// ---------------------------------------------------------------------------
// LayerNorm rows of x (32768) and latents (8192) -> bf16 packed kvin
// kvin[bt][0..255][1024] = xn rows, kvin[bt][256..319][1024] = zn rows
// ---------------------------------------------------------------------------
__global__ __launch_bounds__(256) void ln_kernel(
        const float* __restrict__ x, const float* __restrict__ lat,
        const float* __restrict__ gm, const float* __restrict__ bm,
        const float* __restrict__ gl, const float* __restrict__ bl,
        const int* __restrict__ maskN,
        unsigned short* __restrict__ kvin) {
    int row = blockIdx.x;
    const float* src; unsigned short* dst; const float* g; const float* b;
    int bt;
    if (row < NBT_ * NX_) {
        bt = row >> 8;
        src = x + (size_t)row * D_;
        dst = kvin + ((size_t)bt * NKEY_ + (row & 255)) * D_;
        g = gm; b = bm;
    } else {
        int r = row - NBT_ * NX_;
        bt = r >> 6;
        src = lat + (size_t)r * D_;
        dst = kvin + ((size_t)bt * NKEY_ + 256 + (r & 63)) * D_;
        g = gl; b = bl;
    }
    if (!maskN[bt]) return;                  // masked (b,t): values never read
    int t = threadIdx.x;
    float4 v = reinterpret_cast<const float4*>(src)[t];
    float s  = v.x + v.y + v.z + v.w;
    float sq = v.x * v.x + v.y * v.y + v.z * v.z + v.w * v.w;
    #pragma unroll
    for (int off = 32; off > 0; off >>= 1) {
        s  += __shfl_down(s, off);
        sq += __shfl_down(sq, off);
    }
    __shared__ float red[8];
    int wid = t >> 6;
    if ((t & 63) == 0) { red[wid] = s; red[4 + wid] = sq; }
    __syncthreads();
    float stot = red[0] + red[1] + red[2] + red[3];
    float qtot = red[4] + red[5] + red[6] + red[7];
    float mean = stot * (1.0f / 1024.0f);
    float var  = qtot * (1.0f / 1024.0f) - mean * mean;
    float rstd = rsqrtf(var + 1e-5f);
    float4 gv = reinterpret_cast<const float4*>(g)[t];
    float4 bv = reinterpret_cast<const float4*>(b)[t];
    ushort4 o;
    o.x = f2bf((v.x - mean) * rstd * gv.x + bv.x);
    o.y = f2bf((v.y - mean) * rstd * gv.y + bv.y);
    o.z = f2bf((v.z - mean) * rstd * gv.z + bv.z);
    o.w = f2bf((v.w - mean) * rstd * gv.w + bv.w);
    *reinterpret_cast<ushort4*>(dst + 4 * t) = o;
}

// ---------------------------------------------------------------------------
// 2-phase dbuf GEMM with COUNTED vmcnt (T4): 128x128 tile, BK=64, 4 waves.
// Raw s_barrier + s_waitcnt vmcnt(8): the 8 prefetch loads for tile k+1 stay
// in flight across both barriers; only tile-k's 8 loads are waited on.
// MODE 0: q  [8192][512]  = kvin-z rows @ WqT,  *0.125, bf16
// MODE 1: kv [40960][1024]= kvin @ WkvT -> k [bt][320][512], vT [bt][512][320]
// MODE 2: out[8192][1024] = ao @ WoT, f32, zeros for masked rows
// ---------------------------------------------------------------------------
template<int MODE>
__global__ __launch_bounds__(256) void gemm128_kernel(
        const unsigned short* __restrict__ A,
        const unsigned short* __restrict__ BT,
        const int* __restrict__ maskN,
        unsigned short* __restrict__ o_q,
        unsigned short* __restrict__ o_k,
        unsigned short* __restrict__ o_v,
        float* __restrict__ o_f) {
    constexpr int K     = (MODE == 2) ? 512 : 1024;
    constexpr int NSTEP = K / 64;
    constexpr int NT    = (MODE == 0) ? 4 : 8;                 // N-tiles
    constexpr int CHUNK = (MODE == 1) ? 320 : (MODE == 0 ? 32 : 64);

    int swz = (blockIdx.x & 7) * CHUNK + (blockIdx.x >> 3);    // XCD-chunked
    int nt = swz % NT, mt = swz / NT;
    int m0 = mt * 128, n0 = nt * 128;
    int t = threadIdx.x;
    int lane = t & 63, wid = t >> 6;
    int lr = lane & 15, lg = lane >> 4;
    int wm = wid >> 1, wn = wid & 1;

    // mask skip: which bt's does this row-tile touch?
    int bt0, bt1;
    if (MODE == 1) { bt0 = m0 / NKEY_; bt1 = (m0 + 127) / NKEY_; }
    else           { bt0 = m0 >> 6;    bt1 = bt0 + 1; }
    bool any = false;
    for (int b = bt0; b <= bt1; b++) any |= (maskN[b] != 0);
    if (!any) {
        if (MODE == 2) {                       // masked out rows must be zero
            int r = t >> 1, cb = (t & 1) * 64;
            float4 z = make_float4(0.f, 0.f, 0.f, 0.f);
            float4* p = reinterpret_cast<float4*>(o_f + (size_t)(m0 + r) * 1024 + n0 + cb);
            #pragma unroll
            for (int j = 0; j < 16; j++) p[j] = z;
        }
        return;
    }

    __shared__ __align__(16) unsigned short As[2][8192];   // 2 x 128x64
    __shared__ __align__(16) unsigned short Bs[2][8192];

    // per-lane global staging pointers (rows fixed, col advances)
    const unsigned short* aptr[4];
    const unsigned short* bptr[4];
    #pragma unroll
    for (int i = 0; i < 4; i++) {
        int row = m0 + wid * 32 + i * 8 + (lane >> 3);
        size_t srow;
        if (MODE == 0) { int bt = row >> 6; srow = (size_t)bt * NKEY_ + 256 + (row & 63); }
        else           srow = (size_t)row;
        aptr[i] = A  + srow * K + (lane & 7) * 8;
        int brow = n0 + wid * 32 + i * 8 + (lane >> 3);
        bptr[i] = BT + (size_t)brow * K + (lane & 7) * 8;
    }

    f32x4 acc[4][4];
    #pragma unroll
    for (int i = 0; i < 4; i++)
        #pragma unroll
        for (int j = 0; j < 4; j++) acc[i][j] = (f32x4){0.f, 0.f, 0.f, 0.f};

    auto stage = [&](int buf) {
        unsigned short* as = &As[buf][wid * 2048];
        unsigned short* bs = &Bs[buf][wid * 2048];
        #pragma unroll
        for (int i = 0; i < 4; i++) {
            async16(as + i * 512, aptr[i]);
            async16(bs + i * 512, bptr[i]);
            aptr[i] += 64; bptr[i] += 64;
        }
    };
    auto compute = [&](int buf) {
        #pragma unroll
        for (int kc = 0; kc < 2; kc++) {
            short8 af[4], bf[4];
            #pragma unroll
            for (int mi = 0; mi < 4; mi++)
                af[mi] = *reinterpret_cast<const short8*>(
                    &As[buf][(wm * 64 + mi * 16 + lr) * 64 + kc * 32 + lg * 8]);
            #pragma unroll
            for (int ni = 0; ni < 4; ni++)
                bf[ni] = *reinterpret_cast<const short8*>(
                    &Bs[buf][(wn * 64 + ni * 16 + lr) * 64 + kc * 32 + lg * 8]);
            #pragma unroll
            for (int mi = 0; mi < 4; mi++)
                #pragma unroll
                for (int ni = 0; ni < 4; ni++)
                    acc[mi][ni] = __builtin_amdgcn_mfma_f32_16x16x32_bf16(
                        af[mi], bf[ni], acc[mi][ni], 0, 0, 0);
        }
    };

    // FULL_STEP: stage next tile into buf^1, wait ONLY for tile-k's 8 loads
    // (vmcnt(8): the 8 just-issued prefetch loads remain in flight), compute.
    #define FULL_STEP(CUR)                                              \
        stage((CUR) ^ 1);                                               \
        asm volatile("s_waitcnt vmcnt(8)" ::: "memory");                \
        __builtin_amdgcn_s_barrier();                                   \
        compute(CUR);                                                   \
        asm volatile("s_waitcnt lgkmcnt(0)" ::: "memory");              \
        __builtin_amdgcn_s_barrier();

    stage(0);                                  // prologue: 8 loads in flight
    #pragma unroll 1
    for (int ks2 = 0; ks2 < NSTEP / 2 - 1; ks2++) {
        FULL_STEP(0)
        FULL_STEP(1)
    }
    FULL_STEP(0)                               // step NSTEP-2
    asm volatile("s_waitcnt vmcnt(0)" ::: "memory");   // last tile: drain
    __builtin_amdgcn_s_barrier();
    compute(1);                                // step NSTEP-1 (NSTEP even)
    #undef FULL_STEP

    #pragma unroll
    for (int mi = 0; mi < 4; mi++)
        #pragma unroll
        for (int ni = 0; ni < 4; ni++) {
            int gr0 = m0 + wm * 64 + mi * 16 + lg * 4;     // +r, never crosses bt
            int c   = n0 + wn * 64 + ni * 16 + lr;
            if (MODE == 0) {
                #pragma unroll
                for (int r = 0; r < 4; r++)
                    o_q[(size_t)(gr0 + r) * 512 + c] = f2bf(acc[mi][ni][r] * 0.125f);
            } else if (MODE == 1) {
                int bt = gr0 / NKEY_;
                int krow = gr0 - bt * NKEY_;
                if (c < 512) {
                    #pragma unroll
                    for (int r = 0; r < 4; r++)
                        o_k[((size_t)bt * NKEY_ + krow + r) * 512 + c] = f2bf(acc[mi][ni][r]);
                } else {
                    ushort4 pv;
                    pv.x = f2bf(acc[mi][ni][0]); pv.y = f2bf(acc[mi][ni][1]);
                    pv.z = f2bf(acc[mi][ni][2]); pv.w = f2bf(acc[mi][ni][3]);
                    *reinterpret_cast<ushort4*>(
                        o_v + ((size_t)bt * 512 + (c - 512)) * NKEY_ + krow) = pv;
                }
            } else {
                int bt = gr0 >> 6;
                bool live = maskN[bt] != 0;
                #pragma unroll
                for (int r = 0; r < 4; r++)
                    o_f[(size_t)(gr0 + r) * 1024 + c] = live ? acc[mi][ni][r] : 0.0f;
            }
        }
}

// ---------------------------------------------------------------------------
// fused attention per (b,t,h): sim = q @ k^T (64x320), softmax, out = attn @ v
// ---------------------------------------------------------------------------
__global__ __launch_bounds__(256) void attn_kernel(
        const unsigned short* __restrict__ q,
        const unsigned short* __restrict__ kbuf,
        const unsigned short* __restrict__ vbuf,   // vT [bt][512][320]
        const int* __restrict__ maskN,
        unsigned short* __restrict__ ao) {
    const int nwg = gridDim.x;                     // 1024
    int bid = (blockIdx.x & 7) * (nwg >> 3) + (blockIdx.x >> 3);
    int bt = bid >> 3, h = bid & 7;
    if (!maskN[bt]) return;
    int t = threadIdx.x, w = t >> 6, lane = t & 63;
    int lr = lane & 15, lg = lane >> 4;
    __shared__ __align__(16) unsigned short attn_s[4][16][328];

    const unsigned short* qrow = q + ((size_t)bt * 64 + w * 16 + lr) * 512 + h * 64;
    short8 qa0 = *reinterpret_cast<const short8*>(qrow + lg * 8);
    short8 qa1 = *reinterpret_cast<const short8*>(qrow + 32 + lg * 8);

    f32x4 acc[20];
    #pragma unroll
    for (int i = 0; i < 20; i++) acc[i] = (f32x4){0.f, 0.f, 0.f, 0.f};

    const unsigned short* kb = kbuf + (size_t)bt * NKEY_ * 512 + h * 64;
    #pragma unroll
    for (int nt2 = 0; nt2 < 20; nt2++) {
        const unsigned short* krow = kb + (size_t)(nt2 * 16 + lr) * 512;
        short8 b0 = *reinterpret_cast<const short8*>(krow + lg * 8);
        short8 b1 = *reinterpret_cast<const short8*>(krow + 32 + lg * 8);
        acc[nt2] = __builtin_amdgcn_mfma_f32_16x16x32_bf16(qa0, b0, acc[nt2], 0, 0, 0);
        acc[nt2] = __builtin_amdgcn_mfma_f32_16x16x32_bf16(qa1, b1, acc[nt2], 0, 0, 0);
    }

    float mx[4], sm[4];
    #pragma unroll
    for (int r = 0; r < 4; r++) mx[r] = -1e30f;
    #pragma unroll
    for (int nt2 = 0; nt2 < 20; nt2++)
        #pragma unroll
        for (int r = 0; r < 4; r++) mx[r] = fmaxf(mx[r], acc[nt2][r]);
    #pragma unroll
    for (int r = 0; r < 4; r++) {
        #pragma unroll
        for (int off = 1; off < 16; off <<= 1)
            mx[r] = fmaxf(mx[r], __shfl_xor(mx[r], off));
        sm[r] = 0.f;
    }
    #pragma unroll
    for (int nt2 = 0; nt2 < 20; nt2++)
        #pragma unroll
        for (int r = 0; r < 4; r++) {
            float p = __expf(acc[nt2][r] - mx[r]);
            acc[nt2][r] = p;
            sm[r] += p;
        }
    #pragma unroll
    for (int r = 0; r < 4; r++) {
        #pragma unroll
        for (int off = 1; off < 16; off <<= 1)
            sm[r] += __shfl_xor(sm[r], off);
        sm[r] = 1.0f / sm[r];
    }
    #pragma unroll
    for (int nt2 = 0; nt2 < 20; nt2++)
        #pragma unroll
        for (int r = 0; r < 4; r++)
            attn_s[w][lg * 4 + r][nt2 * 16 + lr] = f2bf(acc[nt2][r] * sm[r]);
    __syncthreads();

    f32x4 o[4];
    #pragma unroll
    for (int i = 0; i < 4; i++) o[i] = (f32x4){0.f, 0.f, 0.f, 0.f};
    const unsigned short* vb = vbuf + (size_t)bt * 512 * NKEY_ + (size_t)h * 64 * NKEY_;
    #pragma unroll
    for (int kc = 0; kc < 10; kc++) {
        short8 pa = *reinterpret_cast<const short8*>(&attn_s[w][lr][kc * 32 + lg * 8]);
        #pragma unroll
        for (int ni = 0; ni < 4; ni++) {
            short8 vf = *reinterpret_cast<const short8*>(
                vb + (size_t)(ni * 16 + lr) * NKEY_ + kc * 32 + lg * 8);
            o[ni] = __builtin_amdgcn_mfma_f32_16x16x32_bf16(pa, vf, o[ni], 0, 0, 0);
        }
    }
    #pragma unroll
    for (int ni = 0; ni < 4; ni++)
        #pragma unroll
        for (int r = 0; r < 4; r++)
            ao[((size_t)bt * 64 + w * 16 + lg * 4 + r) * 512 + h * 64 + ni * 16 + lr] =
                f2bf(o[ni][r]);
}

// ---------------------------------------------------------------------------
extern "C" void kernel_launch(void* const* d_in, const int* in_sizes, int n_in,
                              void* d_out, int out_size, void* d_ws, size_t ws_size,
                              hipStream_t stream) {
    const float* x            = (const float*)d_in[0];
    const float* lat          = (const float*)d_in[1];
    const unsigned char* mraw = (const unsigned char*)d_in[2];
    const float* gm           = (const float*)d_in[3];
    const float* bm           = (const float*)d_in[4];
    const float* gl           = (const float*)d_in[5];
    const float* bl           = (const float*)d_in[6];
    const float* Wq           = (const float*)d_in[7];
    const float* Wkv          = (const float*)d_in[8];
    const float* Wo           = (const float*)d_in[9];
    float* out = (float*)d_out;

    char* ws = (char*)d_ws;
    size_t off = 0;
    int* maskN = (int*)(ws + off);             off += 1024;
    unsigned short* WqT  = (unsigned short*)(ws + off); off += 1048576;   // 512*1024*2
    unsigned short* WkvT = (unsigned short*)(ws + off); off += 2097152;   // 1024*1024*2
    unsigned short* WoT  = (unsigned short*)(ws + off); off += 1048576;   // 1024*512*2
    unsigned short* kvin = (unsigned short*)(ws + off); off += 83886080;  // 128*320*1024*2
    unsigned short* qb   = (unsigned short*)(ws + off); off += 8388608;   // 128*64*512*2
    unsigned short* kb   = (unsigned short*)(ws + off); off += 41943040;  // 128*320*512*2
    unsigned short* vb   = (unsigned short*)(ws + off); off += 41943040;  // 128*512*320*2
    unsigned short* ab   = (unsigned short*)(ws + off); off += 8388608;   // 128*64*512*2

    hipLaunchKernelGGL(mask_kernel,  dim3(1),     dim3(64),  0, stream, mraw, maskN);
    hipLaunchKernelGGL(wprep_kernel, dim3(8192),  dim3(256), 0, stream,
                       Wq, Wkv, Wo, WqT, WkvT, WoT);
    hipLaunchKernelGGL(ln_kernel,    dim3(40960), dim3(256), 0, stream,
                       x, lat, gm, bm, gl, bl, maskN, kvin);
    hipLaunchKernelGGL((gemm128_kernel<0>), dim3(256),  dim3(256), 0, stream,
                       kvin, WqT,  maskN, qb, kb, vb, out);
    hipLaunchKernelGGL((gemm128_kernel<1>), dim3(2560), dim3(256), 0, stream,
                       kvin, WkvT, maskN, qb, kb, vb, out);
    hipLaunchKernelGGL(attn_kernel,         dim3(1024), dim3(256), 0, stream,
                       qb, kb, vb, maskN, ab);
    hipLaunchKernelGGL((gemm128_kernel<2>), dim3(512),  dim3(256), 0, stream,
                       ab, WoT,  maskN, qb, kb, vb, out);
}